// Round 1
// baseline (2146.008 us; speedup 1.0000x reference)
//
#include <hip/hip_runtime.h>

// LSTM: B=512, T=1024, D=64, H=128, gates=4H=512, fc head H->64->1.
// One block per 2 batch rows (256 blocks, 512 threads). Thread j owns gate
// row j: W_ih[j,:] (16 float4) + W_hh[j,:] (32 float4) in registers,
// reused across the 2 batch rows. h/x broadcast from LDS.

#define BB 512
#define TT 1024
#define DD 64
#define HH 128
#define GG 512

__device__ __forceinline__ float sigm(float x) {
    return 1.f / (1.f + __expf(-x));
}
__device__ __forceinline__ float tanh_f(float x) {
    // tanh(x) = 1 - 2/(exp(2x)+1); saturates correctly for |x| large
    return 1.f - 2.f / (__expf(2.f * x) + 1.f);
}

__global__ __launch_bounds__(512, 2)
void lstm_fused_kernel(const float* __restrict__ x_seq,
                       const float* __restrict__ W_ih,
                       const float* __restrict__ W_hh,
                       const float* __restrict__ b_ih,
                       const float* __restrict__ b_hh,
                       const float* __restrict__ W1v,
                       const float* __restrict__ b1v,
                       const float* __restrict__ W2v,
                       const float* __restrict__ b2v,
                       float* __restrict__ out)
{
    const int tid = threadIdx.x;
    const int b0  = blockIdx.x * 2;

    __shared__ __align__(16) float xs[2][2][DD];  // [buf][row][d]
    __shared__ __align__(16) float hs[2][HH];     // [row][u]
    __shared__ __align__(16) float gl[2][GG];     // [row][gate]

    // ---- per-thread weight registers (compile-time indexed only) ----
    float4 wih[16];
    float4 whh[32];
#pragma unroll
    for (int k = 0; k < 16; ++k)
        wih[k] = *reinterpret_cast<const float4*>(W_ih + tid * DD + 4 * k);
#pragma unroll
    for (int k = 0; k < 32; ++k)
        whh[k] = *reinterpret_cast<const float4*>(W_hh + tid * HH + 4 * k);
    const float bias = b_ih[tid] + b_hh[tid];

    // ---- init state + first x tile ----
    if (tid < 256) hs[tid >> 7][tid & 127] = 0.f;
    if (tid < 128) {
        const int r = tid >> 6, k = tid & 63;
        xs[0][r][k] = x_seq[((b0 + r) * TT + 0) * DD + k];
    }
    float c_reg = 0.f;
    __syncthreads();

    for (int t = 0; t < TT; ++t) {
        const int cur = t & 1;
        const float4* x0 = reinterpret_cast<const float4*>(xs[cur][0]);
        const float4* x1 = reinterpret_cast<const float4*>(xs[cur][1]);
        const float4* h0 = reinterpret_cast<const float4*>(hs[0]);
        const float4* h1 = reinterpret_cast<const float4*>(hs[1]);

        float a0 = bias, a1 = bias;  // input-proj chains
        float p0 = 0.f,  p1 = 0.f;   // hidden-proj chains
#pragma unroll
        for (int k = 0; k < 16; ++k) {
            const float4 w  = wih[k];
            const float4 v0 = x0[k];
            const float4 v1 = x1[k];
            a0 = fmaf(w.x, v0.x, a0); a1 = fmaf(w.x, v1.x, a1);
            a0 = fmaf(w.y, v0.y, a0); a1 = fmaf(w.y, v1.y, a1);
            a0 = fmaf(w.z, v0.z, a0); a1 = fmaf(w.z, v1.z, a1);
            a0 = fmaf(w.w, v0.w, a0); a1 = fmaf(w.w, v1.w, a1);
        }
#pragma unroll
        for (int k = 0; k < 32; ++k) {
            const float4 w  = whh[k];
            const float4 v0 = h0[k];
            const float4 v1 = h1[k];
            p0 = fmaf(w.x, v0.x, p0); p1 = fmaf(w.x, v1.x, p1);
            p0 = fmaf(w.y, v0.y, p0); p1 = fmaf(w.y, v1.y, p1);
            p0 = fmaf(w.z, v0.z, p0); p1 = fmaf(w.z, v1.z, p1);
            p0 = fmaf(w.w, v0.w, p0); p1 = fmaf(w.w, v1.w, p1);
        }
        gl[0][tid] = a0 + p0;
        gl[1][tid] = a1 + p1;

        // prefetch x(t+1) into the other buffer (safe: its last readers
        // finished before the two barriers of iteration t-1)
        if (t + 1 < TT && tid < 128) {
            const int r = tid >> 6, k = tid & 63;
            xs[cur ^ 1][r][k] = x_seq[((b0 + r) * TT + (t + 1)) * DD + k];
        }
        __syncthreads();

        // ---- LSTM cell: thread (r,u) owns c[r][u] in a register ----
        if (tid < 256) {
            const int r = tid >> 7, u = tid & 127;
            const float gi = gl[r][u];
            const float gf = gl[r][HH + u];
            const float gg = gl[r][2 * HH + u];
            const float go = gl[r][3 * HH + u];
            c_reg = sigm(gf) * c_reg + sigm(gi) * tanh_f(gg);
            hs[r][u] = sigm(go) * tanh_f(c_reg);
        }
        __syncthreads();
    }

    // ---- fused head: z = relu(h @ W1^T + b1); y = z @ W2^T + b2 ----
    // wave 0 (tid 0..63) handles row 0, wave 1 (tid 64..127) row 1.
    if (tid < 128) {
        const int r = tid >> 6, j = tid & 63;
        float z = b1v[j];
        const float4* w1 = reinterpret_cast<const float4*>(W1v + j * HH);
        const float4* hv = reinterpret_cast<const float4*>(hs[r]);
#pragma unroll
        for (int k = 0; k < 32; ++k) {
            const float4 w  = w1[k];
            const float4 h4 = hv[k];
            z = fmaf(w.x, h4.x, z);
            z = fmaf(w.y, h4.y, z);
            z = fmaf(w.z, h4.z, z);
            z = fmaf(w.w, h4.w, z);
        }
        z = fmaxf(z, 0.f) * W2v[j];
#pragma unroll
        for (int off = 32; off; off >>= 1)
            z += __shfl_down(z, off, 64);
        if (j == 0) out[b0 + r] = z + b2v[0];
    }
}

extern "C" void kernel_launch(void* const* d_in, const int* in_sizes, int n_in,
                              void* d_out, int out_size, void* d_ws, size_t ws_size,
                              hipStream_t stream) {
    const float* x_seq = (const float*)d_in[0];
    const float* W_ih  = (const float*)d_in[1];
    const float* W_hh  = (const float*)d_in[2];
    const float* b_ih  = (const float*)d_in[3];
    const float* b_hh  = (const float*)d_in[4];
    const float* W1    = (const float*)d_in[5];
    const float* b1    = (const float*)d_in[6];
    const float* W2    = (const float*)d_in[7];
    const float* b2    = (const float*)d_in[8];
    float* out = (float*)d_out;

    lstm_fused_kernel<<<BB / 2, 512, 0, stream>>>(
        x_seq, W_ih, W_hh, b_ih, b_hh, W1, b1, W2, b2, out);
}

// Round 2
// 2048.658 us; speedup vs baseline: 1.0475x; 1.0475x over previous
//
#include <hip/hip_runtime.h>

// LSTM: B=512, T=1024, D=64, H=128, gates=4H=512, fc head H->64->1.
// One block per 2 batch rows (256 blocks = 1/CU, 512 threads). Thread j owns
// gate row j: W_ih[j,:] (16 float4) + W_hh[j,:] (32 float4) in registers
// (192 VGPRs -> REQUIRES launch_bounds(512,1); (512,2) caps VGPR at 128 and
// the compiler re-fetches weights from L2 every step: ~103 TB of L2 traffic,
// measured 2.3 ms). h/x broadcast from LDS (uniform ds_read = free broadcast).

#define BB 512
#define TT 1024
#define DD 64
#define HH 128
#define GG 512

__device__ __forceinline__ float sigm(float x) {
    return 1.f / (1.f + __expf(-x));
}
__device__ __forceinline__ float tanh_f(float x) {
    return 1.f - 2.f / (__expf(2.f * x) + 1.f);
}

__global__ __launch_bounds__(512, 1)
void lstm_fused_kernel(const float* __restrict__ x_seq,
                       const float* __restrict__ W_ih,
                       const float* __restrict__ W_hh,
                       const float* __restrict__ b_ih,
                       const float* __restrict__ b_hh,
                       const float* __restrict__ W1v,
                       const float* __restrict__ b1v,
                       const float* __restrict__ W2v,
                       const float* __restrict__ b2v,
                       float* __restrict__ out)
{
    const int tid = threadIdx.x;
    const int b0  = blockIdx.x * 2;

    __shared__ __align__(16) float xs[2][2][DD];  // [buf][row][d]
    __shared__ __align__(16) float hs[2][HH];     // [row][u]
    __shared__ __align__(16) float gl[2][GG];     // [row][gate]

    // ---- per-thread weight registers (compile-time indexed only) ----
    float4 wih[16];
    float4 whh[32];
#pragma unroll
    for (int k = 0; k < 16; ++k)
        wih[k] = *reinterpret_cast<const float4*>(W_ih + tid * DD + 4 * k);
#pragma unroll
    for (int k = 0; k < 32; ++k)
        whh[k] = *reinterpret_cast<const float4*>(W_hh + tid * HH + 4 * k);
    const float bias = b_ih[tid] + b_hh[tid];

    // ---- init state + first x tile ----
    if (tid < 256) hs[tid >> 7][tid & 127] = 0.f;
    if (tid < 128) {
        const int r = tid >> 6, k = tid & 63;
        xs[0][r][k] = x_seq[((b0 + r) * TT + 0) * DD + k];
    }
    float c_reg = 0.f;
    __syncthreads();

    const int pr = tid >> 6, pk = tid & 63;  // x-prefetch coords (tid<128)

    for (int t = 0; t < TT; ++t) {
        const int cur = t & 1;

        // issue next-x global load EARLY so its latency hides under the FMAs
        float xpre = 0.f;
        const bool do_pre = (t + 1 < TT) && (tid < 128);
        if (do_pre) xpre = x_seq[((b0 + pr) * TT + (t + 1)) * DD + pk];

        const float4* x0 = reinterpret_cast<const float4*>(xs[cur][0]);
        const float4* x1 = reinterpret_cast<const float4*>(xs[cur][1]);
        const float4* h0 = reinterpret_cast<const float4*>(hs[0]);
        const float4* h1 = reinterpret_cast<const float4*>(hs[1]);

        float a0 = bias, a1 = bias;  // input-proj chains
        float p0 = 0.f,  p1 = 0.f;   // hidden-proj chains
#pragma unroll
        for (int k = 0; k < 16; ++k) {
            const float4 w  = wih[k];
            const float4 v0 = x0[k];
            const float4 v1 = x1[k];
            a0 = fmaf(w.x, v0.x, a0); a1 = fmaf(w.x, v1.x, a1);
            a0 = fmaf(w.y, v0.y, a0); a1 = fmaf(w.y, v1.y, a1);
            a0 = fmaf(w.z, v0.z, a0); a1 = fmaf(w.z, v1.z, a1);
            a0 = fmaf(w.w, v0.w, a0); a1 = fmaf(w.w, v1.w, a1);
        }
#pragma unroll
        for (int k = 0; k < 32; ++k) {
            const float4 w  = whh[k];
            const float4 v0 = h0[k];
            const float4 v1 = h1[k];
            p0 = fmaf(w.x, v0.x, p0); p1 = fmaf(w.x, v1.x, p1);
            p0 = fmaf(w.y, v0.y, p0); p1 = fmaf(w.y, v1.y, p1);
            p0 = fmaf(w.z, v0.z, p0); p1 = fmaf(w.z, v1.z, p1);
            p0 = fmaf(w.w, v0.w, p0); p1 = fmaf(w.w, v1.w, p1);
        }
        gl[0][tid] = a0 + p0;
        gl[1][tid] = a1 + p1;

        if (do_pre) xs[cur ^ 1][pr][pk] = xpre;
        __syncthreads();

        // ---- LSTM cell: thread (r,u) owns c[r][u] in a register ----
        if (tid < 256) {
            const int r = tid >> 7, u = tid & 127;
            const float gi = gl[r][u];
            const float gf = gl[r][HH + u];
            const float gg = gl[r][2 * HH + u];
            const float go = gl[r][3 * HH + u];
            c_reg = sigm(gf) * c_reg + sigm(gi) * tanh_f(gg);
            hs[r][u] = sigm(go) * tanh_f(c_reg);
        }
        __syncthreads();
    }

    // ---- fused head: z = relu(h @ W1^T + b1); y = z @ W2^T + b2 ----
    if (tid < 128) {
        const int r = tid >> 6, j = tid & 63;
        float z = b1v[j];
        const float4* w1 = reinterpret_cast<const float4*>(W1v + j * HH);
        const float4* hv = reinterpret_cast<const float4*>(hs[r]);
#pragma unroll
        for (int k = 0; k < 32; ++k) {
            const float4 w  = w1[k];
            const float4 h4 = hv[k];
            z = fmaf(w.x, h4.x, z);
            z = fmaf(w.y, h4.y, z);
            z = fmaf(w.z, h4.z, z);
            z = fmaf(w.w, h4.w, z);
        }
        z = fmaxf(z, 0.f) * W2v[j];
#pragma unroll
        for (int off = 32; off; off >>= 1)
            z += __shfl_down(z, off, 64);
        if (j == 0) out[b0 + r] = z + b2v[0];
    }
}

extern "C" void kernel_launch(void* const* d_in, const int* in_sizes, int n_in,
                              void* d_out, int out_size, void* d_ws, size_t ws_size,
                              hipStream_t stream) {
    const float* x_seq = (const float*)d_in[0];
    const float* W_ih  = (const float*)d_in[1];
    const float* W_hh  = (const float*)d_in[2];
    const float* b_ih  = (const float*)d_in[3];
    const float* b_hh  = (const float*)d_in[4];
    const float* W1    = (const float*)d_in[5];
    const float* b1    = (const float*)d_in[6];
    const float* W2    = (const float*)d_in[7];
    const float* b2    = (const float*)d_in[8];
    float* out = (float*)d_out;

    lstm_fused_kernel<<<BB / 2, 512, 0, stream>>>(
        x_seq, W_ih, W_hh, b_ih, b_hh, W1, b1, W2, b2, out);
}

// Round 3
// 1332.435 us; speedup vs baseline: 1.6106x; 1.5375x over previous
//
#include <hip/hip_runtime.h>

// LSTM: B=512, T=1024, D=64, H=128, gates=4H=512, fc head H->64->1.
// 256 blocks (1/CU) x 512 threads, 2 batch rows/block. Thread j owns gate
// row j with weights converted to packed fp16 (half2): 32+64 = 96 VGPRs --
// fits under the compiler's 128-VGPR ceiling (fp32 needed 192 and the
// allocator refused, re-fetching weights from L2 every step: 2.0-2.6 ms).
// Gate math: v_dot2_f32_f16 (2 MAC/instr, fp32 accumulate) on f16 h/x
// broadcast from LDS. c-state stays fp32 in registers.

#define BB 512
#define TT 1024
#define DD 64
#define HH 128
#define GG 512

typedef _Float16 half2_t __attribute__((ext_vector_type(2)));

__device__ __forceinline__ float dot2(half2_t a, half2_t b, float c) {
#if __has_builtin(__builtin_amdgcn_fdot2)
    return __builtin_amdgcn_fdot2(a, b, c, false);
#else
    return c + (float)a[0] * (float)b[0] + (float)a[1] * (float)b[1];
#endif
}

__device__ __forceinline__ half2_t pack2(float a, float b) {
    half2_t r;
    r[0] = (_Float16)a;
    r[1] = (_Float16)b;
    return r;
}

__device__ __forceinline__ half2_t bc(unsigned int u) {
    return __builtin_bit_cast(half2_t, u);
}

__device__ __forceinline__ float sigm(float x) {
    return 1.f / (1.f + __expf(-x));
}
__device__ __forceinline__ float tanh_f(float x) {
    return 1.f - 2.f / (__expf(2.f * x) + 1.f);
}

__global__ __launch_bounds__(512, 1)
void lstm_fused_kernel(const float* __restrict__ x_seq,
                       const float* __restrict__ W_ih,
                       const float* __restrict__ W_hh,
                       const float* __restrict__ b_ih,
                       const float* __restrict__ b_hh,
                       const float* __restrict__ W1v,
                       const float* __restrict__ b1v,
                       const float* __restrict__ W2v,
                       const float* __restrict__ b2v,
                       float* __restrict__ out)
{
    const int tid = threadIdx.x;
    const int b0  = blockIdx.x * 2;

    __shared__ __align__(16) _Float16 xs[2][2][DD];  // [buf][row][d]  f16
    __shared__ __align__(16) _Float16 hs[2][HH];     // [row][u]       f16
    __shared__ __align__(16) float    gl[2][GG];     // [row][gate]    f32

    // ---- per-thread weights, fp32 -> packed half2 (96 VGPRs) ----
    half2_t wih[32];   // W_ih row j: 64 vals
    half2_t whh[64];   // W_hh row j: 128 vals
#pragma unroll
    for (int k = 0; k < 16; ++k) {
        const float4 w = reinterpret_cast<const float4*>(W_ih + tid * DD)[k];
        wih[2 * k]     = pack2(w.x, w.y);
        wih[2 * k + 1] = pack2(w.z, w.w);
    }
#pragma unroll
    for (int k = 0; k < 32; ++k) {
        const float4 w = reinterpret_cast<const float4*>(W_hh + tid * HH)[k];
        whh[2 * k]     = pack2(w.x, w.y);
        whh[2 * k + 1] = pack2(w.z, w.w);
    }
    const float bias = b_ih[tid] + b_hh[tid];

    // ---- init state + first x tile ----
    if (tid < 256) hs[tid >> 7][tid & 127] = (_Float16)0.f;
    if (tid < 128) {
        const int r = tid >> 6, k = tid & 63;
        xs[0][r][k] = (_Float16)x_seq[((b0 + r) * TT + 0) * DD + k];
    }
    float c_reg = 0.f;
    __syncthreads();

    const int pr = tid >> 6, pk = tid & 63;  // x-prefetch coords (tid<128)

    for (int t = 0; t < TT; ++t) {
        const int cur = t & 1;

        // issue next-x global load EARLY: latency hides under the dot2s
        float xpre = 0.f;
        const bool do_pre = (t + 1 < TT) && (tid < 128);
        if (do_pre) xpre = x_seq[((b0 + pr) * TT + (t + 1)) * DD + pk];

        const uint4* h0 = reinterpret_cast<const uint4*>(hs[0]);      // 16
        const uint4* h1 = reinterpret_cast<const uint4*>(hs[1]);
        const uint4* x0 = reinterpret_cast<const uint4*>(xs[cur][0]); // 8
        const uint4* x1 = reinterpret_cast<const uint4*>(xs[cur][1]);

        // 4 accumulator chains (2 rows x 2 partials) hide VALU latency
        float a0 = bias, b0a = 0.f;   // row 0
        float a1 = bias, b1a = 0.f;   // row 1
#pragma unroll
        for (int k = 0; k < 16; ++k) {  // hidden part: 128 vals = 16 uint4
            const uint4 v0 = h0[k];
            const uint4 v1 = h1[k];
            a0  = dot2(whh[4 * k + 0], bc(v0.x), a0);
            a1  = dot2(whh[4 * k + 0], bc(v1.x), a1);
            b0a = dot2(whh[4 * k + 1], bc(v0.y), b0a);
            b1a = dot2(whh[4 * k + 1], bc(v1.y), b1a);
            a0  = dot2(whh[4 * k + 2], bc(v0.z), a0);
            a1  = dot2(whh[4 * k + 2], bc(v1.z), a1);
            b0a = dot2(whh[4 * k + 3], bc(v0.w), b0a);
            b1a = dot2(whh[4 * k + 3], bc(v1.w), b1a);
        }
#pragma unroll
        for (int k = 0; k < 8; ++k) {   // input part: 64 vals = 8 uint4
            const uint4 v0 = x0[k];
            const uint4 v1 = x1[k];
            a0  = dot2(wih[4 * k + 0], bc(v0.x), a0);
            a1  = dot2(wih[4 * k + 0], bc(v1.x), a1);
            b0a = dot2(wih[4 * k + 1], bc(v0.y), b0a);
            b1a = dot2(wih[4 * k + 1], bc(v1.y), b1a);
            a0  = dot2(wih[4 * k + 2], bc(v0.z), a0);
            a1  = dot2(wih[4 * k + 2], bc(v1.z), a1);
            b0a = dot2(wih[4 * k + 3], bc(v0.w), b0a);
            b1a = dot2(wih[4 * k + 3], bc(v1.w), b1a);
        }
        gl[0][tid] = a0 + b0a;
        gl[1][tid] = a1 + b1a;

        if (do_pre) xs[cur ^ 1][pr][pk] = (_Float16)xpre;
        __syncthreads();

        // ---- LSTM cell: thread (r,u) owns c[r][u] in a register ----
        if (tid < 256) {
            const int r = tid >> 7, u = tid & 127;
            const float gi = gl[r][u];
            const float gf = gl[r][HH + u];
            const float gg = gl[r][2 * HH + u];
            const float go = gl[r][3 * HH + u];
            c_reg = sigm(gf) * c_reg + sigm(gi) * tanh_f(gg);
            hs[r][u] = (_Float16)(sigm(go) * tanh_f(c_reg));
        }
        __syncthreads();
    }

    // ---- fused head: z = relu(h @ W1^T + b1); y = z @ W2^T + b2 ----
    if (tid < 128) {
        const int r = tid >> 6, j = tid & 63;
        float z = b1v[j];
        const float* w1 = W1v + j * HH;
#pragma unroll 16
        for (int k = 0; k < HH; ++k)
            z = fmaf(w1[k], (float)hs[r][k], z);
        z = fmaxf(z, 0.f) * W2v[j];
#pragma unroll
        for (int off = 32; off; off >>= 1)
            z += __shfl_down(z, off, 64);
        if (j == 0) out[b0 + r] = z + b2v[0];
    }
}

extern "C" void kernel_launch(void* const* d_in, const int* in_sizes, int n_in,
                              void* d_out, int out_size, void* d_ws, size_t ws_size,
                              hipStream_t stream) {
    const float* x_seq = (const float*)d_in[0];
    const float* W_ih  = (const float*)d_in[1];
    const float* W_hh  = (const float*)d_in[2];
    const float* b_ih  = (const float*)d_in[3];
    const float* b_hh  = (const float*)d_in[4];
    const float* W1    = (const float*)d_in[5];
    const float* b1    = (const float*)d_in[6];
    const float* W2    = (const float*)d_in[7];
    const float* b2    = (const float*)d_in[8];
    float* out = (float*)d_out;

    lstm_fused_kernel<<<BB / 2, 512, 0, stream>>>(
        x_seq, W_ih, W_hh, b_ih, b_hh, W1, b1, W2, b2, out);
}